// Round 8
// baseline (104.888 us; speedup 1.0000x reference)
//
#include <hip/hip_runtime.h>
#include <math.h>

#define DIM 128
#define H 8
#define DK 16
#define BM 64
#define LDB 136   // u16 row stride for bf16 W tile in LDS

typedef __attribute__((ext_vector_type(8))) short short8;
typedef __attribute__((ext_vector_type(4))) float f32x4;
typedef unsigned short u16;
typedef unsigned int u32;

__device__ inline u16 f2bf(float f) {               // fp32 -> bf16 RNE
    union { float f; u32 u; } v; v.f = f;
    u32 r = v.u + 0x7fffu + ((v.u >> 16) & 1u);
    return (u16)(r >> 16);
}
__device__ inline float bfl(u32 u) { union { u32 u; float f; } v; v.u = u << 16; return v.f; }
__device__ inline float bfh(u32 u) { union { u32 u; float f; } v; v.u = u & 0xffff0000u; return v.f; }

// ---- fused q/k/v MFMA projections (one dispatch) ----
// blocks [0,gq): q <- feat_dst/Wq -> qo[n_dst][128]
// [gq,gq+gs): k <- feat_src/Wk2 -> kvo[.][0..127]; rest: v -> kvo[.][128..255]
__global__ __launch_bounds__(256, 4)
void proj_qkv(const float* __restrict__ fsrc, const float* __restrict__ fdst,
              const float* __restrict__ Wq, const float* __restrict__ bq,
              const float* __restrict__ Wk2, const float* __restrict__ bk2,
              const float* __restrict__ Wv, const float* __restrict__ bv,
              u16* __restrict__ qo, u16* __restrict__ kvo,
              int n_dst, int n_src, int gq, int gs) {
    __shared__ __align__(16) u16 wl[DIM * LDB];
    const int bid = blockIdx.x;
    const float *X, *W, *B; u16* Y; int n, tile, ldy, coff;
    if (bid < gq)           { X = fdst; W = Wq;  B = bq;  Y = qo;  n = n_dst; tile = bid;           ldy = 128; coff = 0; }
    else if (bid < gq + gs) { X = fsrc; W = Wk2; B = bk2; Y = kvo; n = n_src; tile = bid - gq;      ldy = 256; coff = 0; }
    else                    { X = fsrc; W = Wv;  B = bv;  Y = kvo; n = n_src; tile = bid - gq - gs; ldy = 256; coff = 128; }

    const int tid = threadIdx.x;
#pragma unroll
    for (int it = 0; it < 8; ++it) {
        int c8 = it * 256 + tid;
        int row = c8 >> 4, ck = c8 & 15;
        const float4* s = (const float4*)&W[(size_t)row * DIM + ck * 8];
        float4 f0 = s[0], f1 = s[1];
        short8 u;
        u[0] = (short)f2bf(f0.x); u[1] = (short)f2bf(f0.y);
        u[2] = (short)f2bf(f0.z); u[3] = (short)f2bf(f0.w);
        u[4] = (short)f2bf(f1.x); u[5] = (short)f2bf(f1.y);
        u[6] = (short)f2bf(f1.z); u[7] = (short)f2bf(f1.w);
        *(short8*)&wl[row * LDB + ck * 8] = u;
    }
    __syncthreads();
    const int lane = tid & 63, wave = tid >> 6;
    const int lrow = lane & 15, kg = lane >> 4;
    const int rbase = tile * BM + wave * 16;
    int xr = rbase + lrow; if (xr > n - 1) xr = n - 1;
    const float* xp = X + (size_t)xr * DIM + kg * 8;

    f32x4 acc[8];
#pragma unroll
    for (int j = 0; j < 8; ++j) acc[j] = (f32x4){0.f, 0.f, 0.f, 0.f};

#pragma unroll
    for (int kc = 0; kc < 4; ++kc) {
        float4 a0 = *(const float4*)(xp + kc * 32);
        float4 a1 = *(const float4*)(xp + kc * 32 + 4);
        short8 af;
        af[0] = (short)f2bf(a0.x); af[1] = (short)f2bf(a0.y);
        af[2] = (short)f2bf(a0.z); af[3] = (short)f2bf(a0.w);
        af[4] = (short)f2bf(a1.x); af[5] = (short)f2bf(a1.y);
        af[6] = (short)f2bf(a1.z); af[7] = (short)f2bf(a1.w);
#pragma unroll
        for (int j = 0; j < 8; ++j) {
            short8 bf = *(const short8*)&wl[(j * 16 + lrow) * LDB + kc * 32 + kg * 8];
            acc[j] = __builtin_amdgcn_mfma_f32_16x16x32_bf16(af, bf, acc[j], 0, 0, 0);
        }
    }
#pragma unroll
    for (int r = 0; r < 4; ++r) {
        int gr = rbase + kg * 4 + r;
        if (gr < n) {
#pragma unroll
            for (int j = 0; j < 8; ++j) {
                int c = j * 16 + lrow;
                Y[(size_t)gr * ldy + coff + c] = f2bf(acc[j][r] + B[c]);
            }
        }
    }
}

// ---- MFMA bf16 GEMM, bf16 X input, fp32 out (final projection) ----
__global__ __launch_bounds__(256, 4)
void gemm_mfma_b(const u16* __restrict__ X, const float* __restrict__ W,
                 const float* __restrict__ b, float* __restrict__ Y, int n) {
    __shared__ __align__(16) u16 wl[DIM * LDB];
    const int tid = threadIdx.x;
#pragma unroll
    for (int it = 0; it < 8; ++it) {
        int c8 = it * 256 + tid;
        int row = c8 >> 4, ck = c8 & 15;
        const float4* s = (const float4*)&W[(size_t)row * DIM + ck * 8];
        float4 f0 = s[0], f1 = s[1];
        short8 u;
        u[0] = (short)f2bf(f0.x); u[1] = (short)f2bf(f0.y);
        u[2] = (short)f2bf(f0.z); u[3] = (short)f2bf(f0.w);
        u[4] = (short)f2bf(f1.x); u[5] = (short)f2bf(f1.y);
        u[6] = (short)f2bf(f1.z); u[7] = (short)f2bf(f1.w);
        *(short8*)&wl[row * LDB + ck * 8] = u;
    }
    __syncthreads();
    const int lane = tid & 63, wave = tid >> 6;
    const int lrow = lane & 15, kg = lane >> 4;
    const int rbase = blockIdx.x * BM + wave * 16;
    int xr = rbase + lrow; if (xr > n - 1) xr = n - 1;
    const u16* xp = X + (size_t)xr * DIM + kg * 8;

    f32x4 acc[8];
#pragma unroll
    for (int j = 0; j < 8; ++j) acc[j] = (f32x4){0.f, 0.f, 0.f, 0.f};

#pragma unroll
    for (int kc = 0; kc < 4; ++kc) {
        short8 af = *(const short8*)(xp + kc * 32);
#pragma unroll
        for (int j = 0; j < 8; ++j) {
            short8 bf = *(const short8*)&wl[(j * 16 + lrow) * LDB + kc * 32 + kg * 8];
            acc[j] = __builtin_amdgcn_mfma_f32_16x16x32_bf16(af, bf, acc[j], 0, 0, 0);
        }
    }
#pragma unroll
    for (int r = 0; r < 4; ++r) {
        int gr = rbase + kg * 4 + r;
        if (gr < n) {
#pragma unroll
            for (int j = 0; j < 8; ++j) {
                int c = j * 16 + lrow;
                Y[(size_t)gr * DIM + c] = acc[j][r] + b[c];
            }
        }
    }
}

// Fold relation_att into Wk:  Wk2[h*16+e][kin] = sum_d R[h][d][e] * Wk[h*16+d][kin]
__global__ void fold_relation(const float* __restrict__ Wk, const float* __restrict__ bk,
                              const float* __restrict__ R, float* __restrict__ Wk2,
                              float* __restrict__ bk2) {
    const int o = blockIdx.x;
    const int t = threadIdx.x;
    const int h = o >> 4, e = o & 15;
    float acc = 0.f;
#pragma unroll
    for (int d = 0; d < DK; ++d)
        acc = fmaf(R[h * 256 + d * 16 + e], Wk[(size_t)(h * 16 + d) * DIM + t], acc);
    Wk2[(size_t)o * DIM + t] = acc;
    if (t == 0) {
        float bb = 0.f;
#pragma unroll
        for (int d = 0; d < DK; ++d) bb = fmaf(R[h * 256 + d * 16 + e], bk[h * 16 + d], bb);
        bk2[o] = bb;
    }
}

// seg[d] = first edge index with didx >= d  (didx sorted); seg[n_dst] = E
__global__ void seg_bounds(const int* __restrict__ didx, int* __restrict__ seg,
                           int E, int n_dst) {
    int e = blockIdx.x * blockDim.x + threadIdx.x;
    if (e >= E) return;
    int d = didx[e];
    int dp = (e == 0) ? -1 : didx[e - 1];
    for (int x = dp + 1; x <= d; ++x) seg[x] = e;
    if (e == E - 1)
        for (int x = d + 1; x <= n_dst; ++x) seg[x] = E;
}

// ONE WAVE per dst. Thread = (edge slot g = t>>3, head h = t&7); each thread
// owns a full head: in-thread 16-dim dot (no shuffles in loop), one exp per
// (edge,head), private 16-dim v accumulator. No LDS, no barriers; kv rows
// interleaved (k cols 0..127, v cols 128..255 of a 512B record). Final
// reduction: 3 shfl_xor over edge-slot strides.
__global__ __launch_bounds__(64)
void edge_attn6(const u16* __restrict__ q, const u16* __restrict__ kv,
                const int* __restrict__ sidx, const int* __restrict__ seg,
                u16* __restrict__ hout) {
    const int dst = blockIdx.x;
    const int t = threadIdx.x;
    const int g = t >> 3, h = t & 7;

    const int s0 = seg[dst], s1 = seg[dst + 1];

    const uint4* qp = (const uint4*)q;
    uint4 qa = qp[(size_t)dst * 16 + h * 2];
    uint4 qb = qp[(size_t)dst * 16 + h * 2 + 1];
    float qf[16];
    qf[0]  = bfl(qa.x); qf[1]  = bfh(qa.x); qf[2]  = bfl(qa.y); qf[3]  = bfh(qa.y);
    qf[4]  = bfl(qa.z); qf[5]  = bfh(qa.z); qf[6]  = bfl(qa.w); qf[7]  = bfh(qa.w);
    qf[8]  = bfl(qb.x); qf[9]  = bfh(qb.x); qf[10] = bfl(qb.y); qf[11] = bfh(qb.y);
    qf[12] = bfl(qb.z); qf[13] = bfh(qb.z); qf[14] = bfl(qb.w); qf[15] = bfh(qb.w);

    const uint4* kvp = (const uint4*)kv;

    float ssum = 0.f;
    float acc[16];
#pragma unroll
    for (int j = 0; j < 16; ++j) acc[j] = 0.f;

#pragma unroll 2
    for (int e = s0 + g; e < s1; e += 8) {
        const int row = sidx[e];
        const uint4* kb = kvp + (size_t)row * 32 + h * 2;
        uint4 k0 = kb[0], k1 = kb[1];
        uint4 v0 = kb[16], v1 = kb[17];
        float d = 0.f;
        d = fmaf(bfl(k0.x), qf[0], d);  d = fmaf(bfh(k0.x), qf[1], d);
        d = fmaf(bfl(k0.y), qf[2], d);  d = fmaf(bfh(k0.y), qf[3], d);
        d = fmaf(bfl(k0.z), qf[4], d);  d = fmaf(bfh(k0.z), qf[5], d);
        d = fmaf(bfl(k0.w), qf[6], d);  d = fmaf(bfh(k0.w), qf[7], d);
        d = fmaf(bfl(k1.x), qf[8], d);  d = fmaf(bfh(k1.x), qf[9], d);
        d = fmaf(bfl(k1.y), qf[10], d); d = fmaf(bfh(k1.y), qf[11], d);
        d = fmaf(bfl(k1.z), qf[12], d); d = fmaf(bfh(k1.z), qf[13], d);
        d = fmaf(bfl(k1.w), qf[14], d); d = fmaf(bfh(k1.w), qf[15], d);
        float lg = d * 0.25f;
        lg = (lg >= 0.f) ? lg : 0.2f * lg;
        const float p = __expf(lg);
        ssum += p;
        acc[0]  = fmaf(p, bfl(v0.x), acc[0]);  acc[1]  = fmaf(p, bfh(v0.x), acc[1]);
        acc[2]  = fmaf(p, bfl(v0.y), acc[2]);  acc[3]  = fmaf(p, bfh(v0.y), acc[3]);
        acc[4]  = fmaf(p, bfl(v0.z), acc[4]);  acc[5]  = fmaf(p, bfh(v0.z), acc[5]);
        acc[6]  = fmaf(p, bfl(v0.w), acc[6]);  acc[7]  = fmaf(p, bfh(v0.w), acc[7]);
        acc[8]  = fmaf(p, bfl(v1.x), acc[8]);  acc[9]  = fmaf(p, bfh(v1.x), acc[9]);
        acc[10] = fmaf(p, bfl(v1.y), acc[10]); acc[11] = fmaf(p, bfh(v1.y), acc[11]);
        acc[12] = fmaf(p, bfl(v1.z), acc[12]); acc[13] = fmaf(p, bfh(v1.z), acc[13]);
        acc[14] = fmaf(p, bfl(v1.w), acc[14]); acc[15] = fmaf(p, bfh(v1.w), acc[15]);
    }

    // reduce over the 8 edge slots (lane strides 8/16/32)
#pragma unroll
    for (int j = 0; j < 16; ++j) {
        acc[j] += __shfl_xor(acc[j], 8);
        acc[j] += __shfl_xor(acc[j], 16);
        acc[j] += __shfl_xor(acc[j], 32);
    }
    ssum += __shfl_xor(ssum, 8);
    ssum += __shfl_xor(ssum, 16);
    ssum += __shfl_xor(ssum, 32);

    if (g == 0) {
        const float inv = (ssum > 0.f) ? 1.f / ssum : 0.f;
        u16 o[16];
#pragma unroll
        for (int j = 0; j < 16; ++j) o[j] = f2bf(acc[j] * inv);
        uint4 pa, pb;
        pa.x = (u32)o[0]  | ((u32)o[1]  << 16);
        pa.y = (u32)o[2]  | ((u32)o[3]  << 16);
        pa.z = (u32)o[4]  | ((u32)o[5]  << 16);
        pa.w = (u32)o[6]  | ((u32)o[7]  << 16);
        pb.x = (u32)o[8]  | ((u32)o[9]  << 16);
        pb.y = (u32)o[10] | ((u32)o[11] << 16);
        pb.z = (u32)o[12] | ((u32)o[13] << 16);
        pb.w = (u32)o[14] | ((u32)o[15] << 16);
        ((uint4*)hout)[(size_t)dst * 16 + h * 2]     = pa;
        ((uint4*)hout)[(size_t)dst * 16 + h * 2 + 1] = pb;
    }
}

extern "C" void kernel_launch(void* const* d_in, const int* in_sizes, int n_in,
                              void* d_out, int out_size, void* d_ws, size_t ws_size,
                              hipStream_t stream) {
    const float* feat_src = (const float*)d_in[0];
    const float* feat_dst = (const float*)d_in[1];
    const int*   src_idx  = (const int*)d_in[2];
    const int*   dst_idx  = (const int*)d_in[3];
    const float* Wq = (const float*)d_in[4];
    const float* bq = (const float*)d_in[5];
    const float* Wk = (const float*)d_in[6];
    const float* bk = (const float*)d_in[7];
    const float* Wv = (const float*)d_in[8];
    const float* bv = (const float*)d_in[9];
    const float* R  = (const float*)d_in[10];
    const float* Wo = (const float*)d_in[11];
    const float* bo = (const float*)d_in[12];

    const int n_src = in_sizes[0] / DIM;
    const int n_dst = in_sizes[1] / DIM;
    const int E     = in_sizes[2];

    float* out = (float*)d_out;
    u16* q   = (u16*)d_ws;                              // n_dst x 128 bf16
    u16* kv  = q  + (size_t)n_dst * DIM;                // n_src x 256 bf16 (k|v)
    u16* hag = kv + (size_t)n_src * 2 * DIM;            // n_dst x 128 bf16
    int* seg = (int*)(hag + (size_t)n_dst * DIM);       // n_dst+1 ints
    size_t segEnd = ((size_t)(n_dst + 1) + 3) & ~(size_t)3;
    float* Wk2 = (float*)(seg + segEnd);                // 128x128 fp32
    float* bk2 = Wk2 + DIM * DIM;                       // 128 fp32

    const int gq = (n_dst + BM - 1) / BM;
    const int gs = (n_src + BM - 1) / BM;

    seg_bounds<<<(E + 255) / 256, 256, 0, stream>>>(dst_idx, seg, E, n_dst);
    fold_relation<<<DIM, DIM, 0, stream>>>(Wk, bk, R, Wk2, bk2);
    proj_qkv<<<gq + 2 * gs, 256, 0, stream>>>(feat_src, feat_dst, Wq, bq, Wk2, bk2,
                                              Wv, bv, q, kv, n_dst, n_src, gq, gs);
    edge_attn6<<<n_dst, 64, 0, stream>>>(q, kv, src_idx, seg, hag);
    gemm_mfma_b<<<gq, 256, 0, stream>>>(hag, Wo, bo, out, n_dst);
}

// Round 9
// 103.683 us; speedup vs baseline: 1.0116x; 1.0116x over previous
//
#include <hip/hip_runtime.h>
#include <math.h>

#define DIM 128
#define H 8
#define DK 16
#define BM 64
#define LDB 136   // u16 row stride for bf16 W tile in LDS

typedef __attribute__((ext_vector_type(8))) short short8;
typedef __attribute__((ext_vector_type(4))) float f32x4;
typedef unsigned short u16;
typedef unsigned int u32;

__device__ inline u16 f2bf(float f) {               // fp32 -> bf16 RNE
    union { float f; u32 u; } v; v.f = f;
    u32 r = v.u + 0x7fffu + ((v.u >> 16) & 1u);
    return (u16)(r >> 16);
}
__device__ inline float bfl(u32 u) { union { u32 u; float f; } v; v.u = u << 16; return v.f; }
__device__ inline float bfh(u32 u) { union { u32 u; float f; } v; v.u = u & 0xffff0000u; return v.f; }

// ---- fused q/k/v MFMA projections (one dispatch) ----
// blocks [0,gq): q <- feat_dst/Wq -> qo[n_dst][128]
// [gq,gq+gs): k <- feat_src/Wk2 -> kvo[.][0..127]; rest: v -> kvo[.][128..255]
__global__ __launch_bounds__(256, 4)
void proj_qkv(const float* __restrict__ fsrc, const float* __restrict__ fdst,
              const float* __restrict__ Wq, const float* __restrict__ bq,
              const float* __restrict__ Wk2, const float* __restrict__ bk2,
              const float* __restrict__ Wv, const float* __restrict__ bv,
              u16* __restrict__ qo, u16* __restrict__ kvo,
              int n_dst, int n_src, int gq, int gs) {
    __shared__ __align__(16) u16 wl[DIM * LDB];
    const int bid = blockIdx.x;
    const float *X, *W, *B; u16* Y; int n, tile, ldy, coff;
    if (bid < gq)           { X = fdst; W = Wq;  B = bq;  Y = qo;  n = n_dst; tile = bid;           ldy = 128; coff = 0; }
    else if (bid < gq + gs) { X = fsrc; W = Wk2; B = bk2; Y = kvo; n = n_src; tile = bid - gq;      ldy = 256; coff = 0; }
    else                    { X = fsrc; W = Wv;  B = bv;  Y = kvo; n = n_src; tile = bid - gq - gs; ldy = 256; coff = 128; }

    const int tid = threadIdx.x;
#pragma unroll
    for (int it = 0; it < 8; ++it) {
        int c8 = it * 256 + tid;
        int row = c8 >> 4, ck = c8 & 15;
        const float4* s = (const float4*)&W[(size_t)row * DIM + ck * 8];
        float4 f0 = s[0], f1 = s[1];
        short8 u;
        u[0] = (short)f2bf(f0.x); u[1] = (short)f2bf(f0.y);
        u[2] = (short)f2bf(f0.z); u[3] = (short)f2bf(f0.w);
        u[4] = (short)f2bf(f1.x); u[5] = (short)f2bf(f1.y);
        u[6] = (short)f2bf(f1.z); u[7] = (short)f2bf(f1.w);
        *(short8*)&wl[row * LDB + ck * 8] = u;
    }
    __syncthreads();
    const int lane = tid & 63, wave = tid >> 6;
    const int lrow = lane & 15, kg = lane >> 4;
    const int rbase = tile * BM + wave * 16;
    int xr = rbase + lrow; if (xr > n - 1) xr = n - 1;
    const float* xp = X + (size_t)xr * DIM + kg * 8;

    f32x4 acc[8];
#pragma unroll
    for (int j = 0; j < 8; ++j) acc[j] = (f32x4){0.f, 0.f, 0.f, 0.f};

#pragma unroll
    for (int kc = 0; kc < 4; ++kc) {
        float4 a0 = *(const float4*)(xp + kc * 32);
        float4 a1 = *(const float4*)(xp + kc * 32 + 4);
        short8 af;
        af[0] = (short)f2bf(a0.x); af[1] = (short)f2bf(a0.y);
        af[2] = (short)f2bf(a0.z); af[3] = (short)f2bf(a0.w);
        af[4] = (short)f2bf(a1.x); af[5] = (short)f2bf(a1.y);
        af[6] = (short)f2bf(a1.z); af[7] = (short)f2bf(a1.w);
#pragma unroll
        for (int j = 0; j < 8; ++j) {
            short8 bf = *(const short8*)&wl[(j * 16 + lrow) * LDB + kc * 32 + kg * 8];
            acc[j] = __builtin_amdgcn_mfma_f32_16x16x32_bf16(af, bf, acc[j], 0, 0, 0);
        }
    }
#pragma unroll
    for (int r = 0; r < 4; ++r) {
        int gr = rbase + kg * 4 + r;
        if (gr < n) {
#pragma unroll
            for (int j = 0; j < 8; ++j) {
                int c = j * 16 + lrow;
                Y[(size_t)gr * ldy + coff + c] = f2bf(acc[j][r] + B[c]);
            }
        }
    }
}

// ---- MFMA bf16 GEMM, bf16 X input, fp32 out (final projection) ----
__global__ __launch_bounds__(256, 4)
void gemm_mfma_b(const u16* __restrict__ X, const float* __restrict__ W,
                 const float* __restrict__ b, float* __restrict__ Y, int n) {
    __shared__ __align__(16) u16 wl[DIM * LDB];
    const int tid = threadIdx.x;
#pragma unroll
    for (int it = 0; it < 8; ++it) {
        int c8 = it * 256 + tid;
        int row = c8 >> 4, ck = c8 & 15;
        const float4* s = (const float4*)&W[(size_t)row * DIM + ck * 8];
        float4 f0 = s[0], f1 = s[1];
        short8 u;
        u[0] = (short)f2bf(f0.x); u[1] = (short)f2bf(f0.y);
        u[2] = (short)f2bf(f0.z); u[3] = (short)f2bf(f0.w);
        u[4] = (short)f2bf(f1.x); u[5] = (short)f2bf(f1.y);
        u[6] = (short)f2bf(f1.z); u[7] = (short)f2bf(f1.w);
        *(short8*)&wl[row * LDB + ck * 8] = u;
    }
    __syncthreads();
    const int lane = tid & 63, wave = tid >> 6;
    const int lrow = lane & 15, kg = lane >> 4;
    const int rbase = blockIdx.x * BM + wave * 16;
    int xr = rbase + lrow; if (xr > n - 1) xr = n - 1;
    const u16* xp = X + (size_t)xr * DIM + kg * 8;

    f32x4 acc[8];
#pragma unroll
    for (int j = 0; j < 8; ++j) acc[j] = (f32x4){0.f, 0.f, 0.f, 0.f};

#pragma unroll
    for (int kc = 0; kc < 4; ++kc) {
        short8 af = *(const short8*)(xp + kc * 32);
#pragma unroll
        for (int j = 0; j < 8; ++j) {
            short8 bf = *(const short8*)&wl[(j * 16 + lrow) * LDB + kc * 32 + kg * 8];
            acc[j] = __builtin_amdgcn_mfma_f32_16x16x32_bf16(af, bf, acc[j], 0, 0, 0);
        }
    }
#pragma unroll
    for (int r = 0; r < 4; ++r) {
        int gr = rbase + kg * 4 + r;
        if (gr < n) {
#pragma unroll
            for (int j = 0; j < 8; ++j) {
                int c = j * 16 + lrow;
                Y[(size_t)gr * DIM + c] = acc[j][r] + b[c];
            }
        }
    }
}

// Fold relation_att into Wk:  Wk2[h*16+e][kin] = sum_d R[h][d][e] * Wk[h*16+d][kin]
__global__ void fold_relation(const float* __restrict__ Wk, const float* __restrict__ bk,
                              const float* __restrict__ R, float* __restrict__ Wk2,
                              float* __restrict__ bk2) {
    const int o = blockIdx.x;
    const int t = threadIdx.x;
    const int h = o >> 4, e = o & 15;
    float acc = 0.f;
#pragma unroll
    for (int d = 0; d < DK; ++d)
        acc = fmaf(R[h * 256 + d * 16 + e], Wk[(size_t)(h * 16 + d) * DIM + t], acc);
    Wk2[(size_t)o * DIM + t] = acc;
    if (t == 0) {
        float bb = 0.f;
#pragma unroll
        for (int d = 0; d < DK; ++d) bb = fmaf(R[h * 256 + d * 16 + e], bk[h * 16 + d], bb);
        bk2[o] = bb;
    }
}

// seg[d] = first edge index with didx >= d  (didx sorted); seg[n_dst] = E
__global__ void seg_bounds(const int* __restrict__ didx, int* __restrict__ seg,
                           int E, int n_dst) {
    int e = blockIdx.x * blockDim.x + threadIdx.x;
    if (e >= E) return;
    int d = didx[e];
    int dp = (e == 0) ? -1 : didx[e - 1];
    for (int x = dp + 1; x <= d; ++x) seg[x] = e;
    if (e == E - 1)
        for (int x = d + 1; x <= n_dst; ++x) seg[x] = E;
}

// ONE WAVE per dst, FOUR dst per 256-thread block (waves independent: no LDS,
// no barriers -> no workgroup-slot occupancy cliff). Thread = (edge slot
// g=lane>>3, head h=lane&7); in-thread 16-dim dot, one exp per (edge,head),
// private v accumulator; kv rows interleaved 512B. 3 shfl_xor final reduce.
__global__ __launch_bounds__(256, 8)
void edge_attn7(const u16* __restrict__ q, const u16* __restrict__ kv,
                const int* __restrict__ sidx, const int* __restrict__ seg,
                u16* __restrict__ hout, int n_dst) {
    const int wave = threadIdx.x >> 6;
    const int lane = threadIdx.x & 63;
    const int dst = blockIdx.x * 4 + wave;
    if (dst >= n_dst) return;
    const int g = lane >> 3, h = lane & 7;

    const int s0 = seg[dst], s1 = seg[dst + 1];

    const uint4* qp = (const uint4*)q;
    uint4 qa = qp[(size_t)dst * 16 + h * 2];
    uint4 qb = qp[(size_t)dst * 16 + h * 2 + 1];
    float qf[16];
    qf[0]  = bfl(qa.x); qf[1]  = bfh(qa.x); qf[2]  = bfl(qa.y); qf[3]  = bfh(qa.y);
    qf[4]  = bfl(qa.z); qf[5]  = bfh(qa.z); qf[6]  = bfl(qa.w); qf[7]  = bfh(qa.w);
    qf[8]  = bfl(qb.x); qf[9]  = bfh(qb.x); qf[10] = bfl(qb.y); qf[11] = bfh(qb.y);
    qf[12] = bfl(qb.z); qf[13] = bfh(qb.z); qf[14] = bfl(qb.w); qf[15] = bfh(qb.w);

    const uint4* kvp = (const uint4*)kv;

    float ssum = 0.f;
    float acc[16];
#pragma unroll
    for (int j = 0; j < 16; ++j) acc[j] = 0.f;

#pragma unroll 2
    for (int e = s0 + g; e < s1; e += 8) {
        const int row = sidx[e];
        const uint4* kb = kvp + (size_t)row * 32 + h * 2;
        uint4 k0 = kb[0], k1 = kb[1];
        uint4 v0 = kb[16], v1 = kb[17];
        float d = 0.f;
        d = fmaf(bfl(k0.x), qf[0], d);  d = fmaf(bfh(k0.x), qf[1], d);
        d = fmaf(bfl(k0.y), qf[2], d);  d = fmaf(bfh(k0.y), qf[3], d);
        d = fmaf(bfl(k0.z), qf[4], d);  d = fmaf(bfh(k0.z), qf[5], d);
        d = fmaf(bfl(k0.w), qf[6], d);  d = fmaf(bfh(k0.w), qf[7], d);
        d = fmaf(bfl(k1.x), qf[8], d);  d = fmaf(bfh(k1.x), qf[9], d);
        d = fmaf(bfl(k1.y), qf[10], d); d = fmaf(bfh(k1.y), qf[11], d);
        d = fmaf(bfl(k1.z), qf[12], d); d = fmaf(bfh(k1.z), qf[13], d);
        d = fmaf(bfl(k1.w), qf[14], d); d = fmaf(bfh(k1.w), qf[15], d);
        float lg = d * 0.25f;
        lg = (lg >= 0.f) ? lg : 0.2f * lg;
        const float p = __expf(lg);
        ssum += p;
        acc[0]  = fmaf(p, bfl(v0.x), acc[0]);  acc[1]  = fmaf(p, bfh(v0.x), acc[1]);
        acc[2]  = fmaf(p, bfl(v0.y), acc[2]);  acc[3]  = fmaf(p, bfh(v0.y), acc[3]);
        acc[4]  = fmaf(p, bfl(v0.z), acc[4]);  acc[5]  = fmaf(p, bfh(v0.z), acc[5]);
        acc[6]  = fmaf(p, bfl(v0.w), acc[6]);  acc[7]  = fmaf(p, bfh(v0.w), acc[7]);
        acc[8]  = fmaf(p, bfl(v1.x), acc[8]);  acc[9]  = fmaf(p, bfh(v1.x), acc[9]);
        acc[10] = fmaf(p, bfl(v1.y), acc[10]); acc[11] = fmaf(p, bfh(v1.y), acc[11]);
        acc[12] = fmaf(p, bfl(v1.z), acc[12]); acc[13] = fmaf(p, bfh(v1.z), acc[13]);
        acc[14] = fmaf(p, bfl(v1.w), acc[14]); acc[15] = fmaf(p, bfh(v1.w), acc[15]);
    }

    // reduce over the 8 edge slots (lane strides 8/16/32)
#pragma unroll
    for (int j = 0; j < 16; ++j) {
        acc[j] += __shfl_xor(acc[j], 8);
        acc[j] += __shfl_xor(acc[j], 16);
        acc[j] += __shfl_xor(acc[j], 32);
    }
    ssum += __shfl_xor(ssum, 8);
    ssum += __shfl_xor(ssum, 16);
    ssum += __shfl_xor(ssum, 32);

    if (g == 0) {
        const float inv = (ssum > 0.f) ? 1.f / ssum : 0.f;
        u16 o[16];
#pragma unroll
        for (int j = 0; j < 16; ++j) o[j] = f2bf(acc[j] * inv);
        uint4 pa, pb;
        pa.x = (u32)o[0]  | ((u32)o[1]  << 16);
        pa.y = (u32)o[2]  | ((u32)o[3]  << 16);
        pa.z = (u32)o[4]  | ((u32)o[5]  << 16);
        pa.w = (u32)o[6]  | ((u32)o[7]  << 16);
        pb.x = (u32)o[8]  | ((u32)o[9]  << 16);
        pb.y = (u32)o[10] | ((u32)o[11] << 16);
        pb.z = (u32)o[12] | ((u32)o[13] << 16);
        pb.w = (u32)o[14] | ((u32)o[15] << 16);
        ((uint4*)hout)[(size_t)dst * 16 + h * 2]     = pa;
        ((uint4*)hout)[(size_t)dst * 16 + h * 2 + 1] = pb;
    }
}

extern "C" void kernel_launch(void* const* d_in, const int* in_sizes, int n_in,
                              void* d_out, int out_size, void* d_ws, size_t ws_size,
                              hipStream_t stream) {
    const float* feat_src = (const float*)d_in[0];
    const float* feat_dst = (const float*)d_in[1];
    const int*   src_idx  = (const int*)d_in[2];
    const int*   dst_idx  = (const int*)d_in[3];
    const float* Wq = (const float*)d_in[4];
    const float* bq = (const float*)d_in[5];
    const float* Wk = (const float*)d_in[6];
    const float* bk = (const float*)d_in[7];
    const float* Wv = (const float*)d_in[8];
    const float* bv = (const float*)d_in[9];
    const float* R  = (const float*)d_in[10];
    const float* Wo = (const float*)d_in[11];
    const float* bo = (const float*)d_in[12];

    const int n_src = in_sizes[0] / DIM;
    const int n_dst = in_sizes[1] / DIM;
    const int E     = in_sizes[2];

    float* out = (float*)d_out;
    u16* q   = (u16*)d_ws;                              // n_dst x 128 bf16
    u16* kv  = q  + (size_t)n_dst * DIM;                // n_src x 256 bf16 (k|v)
    u16* hag = kv + (size_t)n_src * 2 * DIM;            // n_dst x 128 bf16
    int* seg = (int*)(hag + (size_t)n_dst * DIM);       // n_dst+1 ints
    size_t segEnd = ((size_t)(n_dst + 1) + 3) & ~(size_t)3;
    float* Wk2 = (float*)(seg + segEnd);                // 128x128 fp32
    float* bk2 = Wk2 + DIM * DIM;                       // 128 fp32

    const int gq = (n_dst + BM - 1) / BM;
    const int gs = (n_src + BM - 1) / BM;

    seg_bounds<<<(E + 255) / 256, 256, 0, stream>>>(dst_idx, seg, E, n_dst);
    fold_relation<<<DIM, DIM, 0, stream>>>(Wk, bk, R, Wk2, bk2);
    proj_qkv<<<gq + 2 * gs, 256, 0, stream>>>(feat_src, feat_dst, Wq, bq, Wk2, bk2,
                                              Wv, bv, q, kv, n_dst, n_src, gq, gs);
    edge_attn7<<<(n_dst + 3) / 4, 256, 0, stream>>>(q, kv, src_idx, seg, hag, n_dst);
    gemm_mfma_b<<<gq, 256, 0, stream>>>(hag, Wo, bo, out, n_dst);
}

// Round 11
// 101.522 us; speedup vs baseline: 1.0332x; 1.0213x over previous
//
#include <hip/hip_runtime.h>
#include <math.h>

#define DIM 128
#define BM 64
#define LDB 136   // u16 row stride for bf16 W tile in LDS (272B)
#define KVREC 384 // bytes per kv record: 128B fp8 k + 256B bf16 v

typedef __attribute__((ext_vector_type(8))) short short8;
typedef __attribute__((ext_vector_type(4))) float f32x4;
typedef __attribute__((ext_vector_type(2))) float f32x2;
typedef unsigned short u16;
typedef unsigned int u32;
typedef unsigned char u8;

__device__ inline u16 f2bf(float f) {               // fp32 -> bf16 RNE
    union { float f; u32 u; } v; v.f = f;
    u32 r = v.u + 0x7fffu + ((v.u >> 16) & 1u);
    return (u16)(r >> 16);
}
__device__ inline float bfl(u32 u) { union { u32 u; float f; } v; v.u = u << 16; return v.f; }
__device__ inline float bfh(u32 u) { union { u32 u; float f; } v; v.u = u & 0xffff0000u; return v.f; }

// fp8 decode: dword w -> 4 floats fused into an fma chain (2 elems per cvt)
#define DEC_FMA(w, q0, q1, q2, q3, d) {                          \
    f32x2 lo_ = __builtin_amdgcn_cvt_pk_f32_fp8((w), false);     \
    f32x2 hi_ = __builtin_amdgcn_cvt_pk_f32_fp8((w), true);      \
    d = fmaf(lo_.x, q0, d); d = fmaf(lo_.y, q1, d);              \
    d = fmaf(hi_.x, q2, d); d = fmaf(hi_.y, q3, d); }

// pack 8 floats -> 8 fp8 bytes (uint2)
#define PACK8(x0,x1,x2,x3,x4,x5,x6,x7, out) {                    \
    int d0_ = __builtin_amdgcn_cvt_pk_fp8_f32(x0, x1, 0, false); \
    d0_ = __builtin_amdgcn_cvt_pk_fp8_f32(x2, x3, d0_, true);    \
    int d1_ = __builtin_amdgcn_cvt_pk_fp8_f32(x4, x5, 0, false); \
    d1_ = __builtin_amdgcn_cvt_pk_fp8_f32(x6, x7, d1_, true);    \
    out.x = (u32)d0_; out.y = (u32)d1_; }

// Wkv[0..127] = fold(R, Wk); Wkv[128..255] = Wv. bkv likewise.
__global__ void fold_relation_kv(const float* __restrict__ Wk, const float* __restrict__ bk,
                                 const float* __restrict__ Wv, const float* __restrict__ bv,
                                 const float* __restrict__ R, float* __restrict__ Wkv,
                                 float* __restrict__ bkv) {
    const int o = blockIdx.x;   // 0..255
    const int t = threadIdx.x;  // 0..127
    if (o < 128) {
        const int h = o >> 4, e = o & 15;
        float acc = 0.f;
#pragma unroll
        for (int d = 0; d < 16; ++d)
            acc = fmaf(R[h * 256 + d * 16 + e], Wk[(size_t)(h * 16 + d) * DIM + t], acc);
        Wkv[(size_t)o * DIM + t] = acc;
        if (t == 0) {
            float bb = 0.f;
#pragma unroll
            for (int d = 0; d < 16; ++d) bb = fmaf(R[h * 256 + d * 16 + e], bk[h * 16 + d], bb);
            bkv[o] = bb;
        }
    } else {
        Wkv[(size_t)o * DIM + t] = Wv[(size_t)(o - 128) * DIM + t];
        if (t == 0) bkv[o] = bv[o - 128];
    }
}

// seg[d] = first edge index with didx >= d  (didx sorted); seg[n_dst] = E
__global__ void seg_bounds(const int* __restrict__ didx, int* __restrict__ seg,
                           int E, int n_dst) {
    int e = blockIdx.x * blockDim.x + threadIdx.x;
    if (e >= E) return;
    int d = didx[e];
    int dp = (e == 0) ? -1 : didx[e - 1];
    for (int x = dp + 1; x <= d; ++x) seg[x] = e;
    if (e == E - 1)
        for (int x = d + 1; x <= n_dst; ++x) seg[x] = E;
}

// Fused projections. Blocks [0,gq): q (bf16). Blocks [gq,gq+gs): k AND v for
// one 64-row feat_src tile (X loaded once), writing 384B records: k fp8 (128B)
// + v bf16 (256B). Weight rows permuted in LDS (row c -> slot (c%8)*16 + c/8)
// so each thread's 8 output cols are contiguous.
__global__ __launch_bounds__(256, 4)
void proj_all(const float* __restrict__ fsrc, const float* __restrict__ fdst,
              const float* __restrict__ Wq, const float* __restrict__ bq,
              const float* __restrict__ Wkv, const float* __restrict__ bkv,
              u16* __restrict__ qo, u8* __restrict__ kvo,
              int n_dst, int n_src, int gq) {
    __shared__ __align__(16) u16 wl[DIM * LDB];
    const int bid = blockIdx.x;
    const bool isQ = bid < gq;
    const int tile = isQ ? bid : bid - gq;
    const float* X = isQ ? fdst : fsrc;
    const int n = isQ ? n_dst : n_src;

    const int tid = threadIdx.x;
    const int lane = tid & 63, wave = tid >> 6;
    const int lrow = lane & 15, kg = lane >> 4;
    const int rbase = tile * BM + wave * 16;
    int xr = rbase + lrow; if (xr > n - 1) xr = n - 1;
    const float* xp = X + (size_t)xr * DIM + kg * 8;

    short8 af[4];
#pragma unroll
    for (int kc = 0; kc < 4; ++kc) {
        float4 a0 = *(const float4*)(xp + kc * 32);
        float4 a1 = *(const float4*)(xp + kc * 32 + 4);
        short8 u;
        u[0] = (short)f2bf(a0.x); u[1] = (short)f2bf(a0.y);
        u[2] = (short)f2bf(a0.z); u[3] = (short)f2bf(a0.w);
        u[4] = (short)f2bf(a1.x); u[5] = (short)f2bf(a1.y);
        u[6] = (short)f2bf(a1.z); u[7] = (short)f2bf(a1.w);
        af[kc] = u;
    }

    const float* W0 = isQ ? Wq : Wkv;
#pragma unroll
    for (int it = 0; it < 8; ++it) {
        int flat = it * 256 + tid;
        int c = flat >> 4, ck = flat & 15;
        int slot = (c & 7) * 16 + (c >> 3);
        const float4* s = (const float4*)&W0[(size_t)c * DIM + ck * 8];
        float4 f0 = s[0], f1 = s[1];
        short8 u;
        u[0] = (short)f2bf(f0.x); u[1] = (short)f2bf(f0.y);
        u[2] = (short)f2bf(f0.z); u[3] = (short)f2bf(f0.w);
        u[4] = (short)f2bf(f1.x); u[5] = (short)f2bf(f1.y);
        u[6] = (short)f2bf(f1.z); u[7] = (short)f2bf(f1.w);
        *(short8*)&wl[slot * LDB + ck * 8] = u;
    }
    __syncthreads();

    f32x4 acck[8];
#pragma unroll
    for (int j = 0; j < 8; ++j) acck[j] = (f32x4){0.f, 0.f, 0.f, 0.f};
#pragma unroll
    for (int kc = 0; kc < 4; ++kc)
#pragma unroll
        for (int j = 0; j < 8; ++j) {
            short8 bf = *(const short8*)&wl[(j * 16 + lrow) * LDB + kc * 32 + kg * 8];
            acck[j] = __builtin_amdgcn_mfma_f32_16x16x32_bf16(af[kc], bf, acck[j], 0, 0, 0);
        }

    f32x4 accv[8];
    if (!isQ) {
        __syncthreads();
#pragma unroll
        for (int it = 0; it < 8; ++it) {
            int flat = it * 256 + tid;
            int c = flat >> 4, ck = flat & 15;
            int slot = (c & 7) * 16 + (c >> 3);
            const float4* s = (const float4*)&Wkv[(size_t)(128 + c) * DIM + ck * 8];
            float4 f0 = s[0], f1 = s[1];
            short8 u;
            u[0] = (short)f2bf(f0.x); u[1] = (short)f2bf(f0.y);
            u[2] = (short)f2bf(f0.z); u[3] = (short)f2bf(f0.w);
            u[4] = (short)f2bf(f1.x); u[5] = (short)f2bf(f1.y);
            u[6] = (short)f2bf(f1.z); u[7] = (short)f2bf(f1.w);
            *(short8*)&wl[slot * LDB + ck * 8] = u;
        }
        __syncthreads();
#pragma unroll
        for (int j = 0; j < 8; ++j) accv[j] = (f32x4){0.f, 0.f, 0.f, 0.f};
#pragma unroll
        for (int kc = 0; kc < 4; ++kc)
#pragma unroll
            for (int j = 0; j < 8; ++j) {
                short8 bf = *(const short8*)&wl[(j * 16 + lrow) * LDB + kc * 32 + kg * 8];
                accv[j] = __builtin_amdgcn_mfma_f32_16x16x32_bf16(af[kc], bf, accv[j], 0, 0, 0);
            }
    }

    if (isQ) {
        float bias[8];
        *(float4*)&bias[0] = *(const float4*)&bq[lrow * 8];
        *(float4*)&bias[4] = *(const float4*)&bq[lrow * 8 + 4];
#pragma unroll
        for (int r = 0; r < 4; ++r) {
            int gr = rbase + kg * 4 + r;
            if (gr < n) {
                u16 o[8];
#pragma unroll
                for (int j = 0; j < 8; ++j) o[j] = f2bf(acck[j][r] + bias[j]);
                uint4 pk;
                pk.x = (u32)o[0] | ((u32)o[1] << 16);
                pk.y = (u32)o[2] | ((u32)o[3] << 16);
                pk.z = (u32)o[4] | ((u32)o[5] << 16);
                pk.w = (u32)o[6] | ((u32)o[7] << 16);
                *(uint4*)&qo[(size_t)gr * DIM + lrow * 8] = pk;
            }
        }
    } else {
        float bk_[8], bv_[8];
        *(float4*)&bk_[0] = *(const float4*)&bkv[lrow * 8];
        *(float4*)&bk_[4] = *(const float4*)&bkv[lrow * 8 + 4];
        *(float4*)&bv_[0] = *(const float4*)&bkv[128 + lrow * 8];
        *(float4*)&bv_[4] = *(const float4*)&bkv[128 + lrow * 8 + 4];
#pragma unroll
        for (int r = 0; r < 4; ++r) {
            int gr = rbase + kg * 4 + r;
            if (gr < n) {
                uint2 kd;
                PACK8(acck[0][r] + bk_[0], acck[1][r] + bk_[1], acck[2][r] + bk_[2],
                      acck[3][r] + bk_[3], acck[4][r] + bk_[4], acck[5][r] + bk_[5],
                      acck[6][r] + bk_[6], acck[7][r] + bk_[7], kd);
                u16 o[8];
#pragma unroll
                for (int j = 0; j < 8; ++j) o[j] = f2bf(accv[j][r] + bv_[j]);
                uint4 vd;
                vd.x = (u32)o[0] | ((u32)o[1] << 16);
                vd.y = (u32)o[2] | ((u32)o[3] << 16);
                vd.z = (u32)o[4] | ((u32)o[5] << 16);
                vd.w = (u32)o[6] | ((u32)o[7] << 16);
                u8* rec = kvo + (size_t)gr * KVREC;
                *(uint2*)(rec + lrow * 8) = kd;
                *(uint4*)(rec + 128 + lrow * 16) = vd;
            }
        }
    }
}

// ---- MFMA bf16 GEMM, bf16 X input, fp32 out (final projection) ----
__global__ __launch_bounds__(256, 4)
void gemm_mfma_b(const u16* __restrict__ X, const float* __restrict__ W,
                 const float* __restrict__ b, float* __restrict__ Y, int n) {
    __shared__ __align__(16) u16 wl[DIM * LDB];
    const int tid = threadIdx.x;
#pragma unroll
    for (int it = 0; it < 8; ++it) {
        int c8 = it * 256 + tid;
        int row = c8 >> 4, ck = c8 & 15;
        const float4* s = (const float4*)&W[(size_t)row * DIM + ck * 8];
        float4 f0 = s[0], f1 = s[1];
        short8 u;
        u[0] = (short)f2bf(f0.x); u[1] = (short)f2bf(f0.y);
        u[2] = (short)f2bf(f0.z); u[3] = (short)f2bf(f0.w);
        u[4] = (short)f2bf(f1.x); u[5] = (short)f2bf(f1.y);
        u[6] = (short)f2bf(f1.z); u[7] = (short)f2bf(f1.w);
        *(short8*)&wl[row * LDB + ck * 8] = u;
    }
    __syncthreads();
    const int lane = tid & 63, wave = tid >> 6;
    const int lrow = lane & 15, kg = lane >> 4;
    const int rbase = blockIdx.x * BM + wave * 16;
    int xr = rbase + lrow; if (xr > n - 1) xr = n - 1;
    const u16* xp = X + (size_t)xr * DIM + kg * 8;

    f32x4 acc[8];
#pragma unroll
    for (int j = 0; j < 8; ++j) acc[j] = (f32x4){0.f, 0.f, 0.f, 0.f};

#pragma unroll
    for (int kc = 0; kc < 4; ++kc) {
        short8 af = *(const short8*)(xp + kc * 32);
#pragma unroll
        for (int j = 0; j < 8; ++j) {
            short8 bf = *(const short8*)&wl[(j * 16 + lrow) * LDB + kc * 32 + kg * 8];
            acc[j] = __builtin_amdgcn_mfma_f32_16x16x32_bf16(af, bf, acc[j], 0, 0, 0);
        }
    }
#pragma unroll
    for (int r = 0; r < 4; ++r) {
        int gr = rbase + kg * 4 + r;
        if (gr < n) {
#pragma unroll
            for (int j = 0; j < 8; ++j) {
                int c = j * 16 + lrow;
                Y[(size_t)gr * DIM + c] = acc[j][r] + b[c];
            }
        }
    }
}

// ONE WAVE per dst, 4 dst per block. Thread = (edge slot g=lane>>3, head
// h=lane&7). 384B records: k fp8 (16B/head-lane), v bf16 (32B/head-lane).
// No LDS, no barriers in loop.
__global__ __launch_bounds__(256, 8)
void edge_attn9(const u16* __restrict__ q, const u8* __restrict__ kv,
                const int* __restrict__ sidx, const int* __restrict__ seg,
                u16* __restrict__ hout, int n_dst) {
    const int wave = threadIdx.x >> 6;
    const int lane = threadIdx.x & 63;
    const int dst = blockIdx.x * 4 + wave;
    if (dst >= n_dst) return;
    const int g = lane >> 3, h = lane & 7;

    const int s0 = seg[dst], s1 = seg[dst + 1];

    const uint4* qp = (const uint4*)q;
    uint4 qa = qp[(size_t)dst * 16 + h * 2];
    uint4 qb = qp[(size_t)dst * 16 + h * 2 + 1];
    float qf[16];
    qf[0]  = bfl(qa.x); qf[1]  = bfh(qa.x); qf[2]  = bfl(qa.y); qf[3]  = bfh(qa.y);
    qf[4]  = bfl(qa.z); qf[5]  = bfh(qa.z); qf[6]  = bfl(qa.w); qf[7]  = bfh(qa.w);
    qf[8]  = bfl(qb.x); qf[9]  = bfh(qb.x); qf[10] = bfl(qb.y); qf[11] = bfh(qb.y);
    qf[12] = bfl(qb.z); qf[13] = bfh(qb.z); qf[14] = bfl(qb.w); qf[15] = bfh(qb.w);

    float ssum = 0.f;
    float acc[16];
#pragma unroll
    for (int j = 0; j < 16; ++j) acc[j] = 0.f;

#pragma unroll 2
    for (int e = s0 + g; e < s1; e += 8) {
        const int row = sidx[e];
        const u8* rec = kv + (size_t)row * KVREC;
        uint4 k4 = *(const uint4*)(rec + h * 16);
        uint4 v0 = *(const uint4*)(rec + 128 + h * 32);
        uint4 v1 = *(const uint4*)(rec + 128 + h * 32 + 16);
        float d = 0.f;
        DEC_FMA(k4.x, qf[0],  qf[1],  qf[2],  qf[3],  d);
        DEC_FMA(k4.y, qf[4],  qf[5],  qf[6],  qf[7],  d);
        DEC_FMA(k4.z, qf[8],  qf[9],  qf[10], qf[11], d);
        DEC_FMA(k4.w, qf[12], qf[13], qf[14], qf[15], d);
        float lg = d * 0.25f;
        lg = (lg >= 0.f) ? lg : 0.2f * lg;
        const float p = __expf(lg);
        ssum += p;
        acc[0]  = fmaf(p, bfl(v0.x), acc[0]);  acc[1]  = fmaf(p, bfh(v0.x), acc[1]);
        acc[2]  = fmaf(p, bfl(v0.y), acc[2]);  acc[3]  = fmaf(p, bfh(v0.y), acc[3]);
        acc[4]  = fmaf(p, bfl(v0.z), acc[4]);  acc[5]  = fmaf(p, bfh(v0.z), acc[5]);
        acc[6]  = fmaf(p, bfl(v0.w), acc[6]);  acc[7]  = fmaf(p, bfh(v0.w), acc[7]);
        acc[8]  = fmaf(p, bfl(v1.x), acc[8]);  acc[9]  = fmaf(p, bfh(v1.x), acc[9]);
        acc[10] = fmaf(p, bfl(v1.y), acc[10]); acc[11] = fmaf(p, bfh(v1.y), acc[11]);
        acc[12] = fmaf(p, bfl(v1.z), acc[12]); acc[13] = fmaf(p, bfh(v1.z), acc[13]);
        acc[14] = fmaf(p, bfl(v1.w), acc[14]); acc[15] = fmaf(p, bfh(v1.w), acc[15]);
    }

#pragma unroll
    for (int j = 0; j < 16; ++j) {
        acc[j] += __shfl_xor(acc[j], 8);
        acc[j] += __shfl_xor(acc[j], 16);
        acc[j] += __shfl_xor(acc[j], 32);
    }
    ssum += __shfl_xor(ssum, 8);
    ssum += __shfl_xor(ssum, 16);
    ssum += __shfl_xor(ssum, 32);

    if (g == 0) {
        const float inv = (ssum > 0.f) ? 1.f / ssum : 0.f;
        u16 o[16];
#pragma unroll
        for (int j = 0; j < 16; ++j) o[j] = f2bf(acc[j] * inv);
        uint4 pa, pb;
        pa.x = (u32)o[0]  | ((u32)o[1]  << 16);
        pa.y = (u32)o[2]  | ((u32)o[3]  << 16);
        pa.z = (u32)o[4]  | ((u32)o[5]  << 16);
        pa.w = (u32)o[6]  | ((u32)o[7]  << 16);
        pb.x = (u32)o[8]  | ((u32)o[9]  << 16);
        pb.y = (u32)o[10] | ((u32)o[11] << 16);
        pb.z = (u32)o[12] | ((u32)o[13] << 16);
        pb.w = (u32)o[14] | ((u32)o[15] << 16);
        ((uint4*)hout)[(size_t)dst * 16 + h * 2]     = pa;
        ((uint4*)hout)[(size_t)dst * 16 + h * 2 + 1] = pb;
    }
}

extern "C" void kernel_launch(void* const* d_in, const int* in_sizes, int n_in,
                              void* d_out, int out_size, void* d_ws, size_t ws_size,
                              hipStream_t stream) {
    const float* feat_src = (const float*)d_in[0];
    const float* feat_dst = (const float*)d_in[1];
    const int*   src_idx  = (const int*)d_in[2];
    const int*   dst_idx  = (const int*)d_in[3];
    const float* Wq = (const float*)d_in[4];
    const float* bq = (const float*)d_in[5];
    const float* Wk = (const float*)d_in[6];
    const float* bk = (const float*)d_in[7];
    const float* Wv = (const float*)d_in[8];
    const float* bv = (const float*)d_in[9];
    const float* R  = (const float*)d_in[10];
    const float* Wo = (const float*)d_in[11];
    const float* bo = (const float*)d_in[12];

    const int n_src = in_sizes[0] / DIM;
    const int n_dst = in_sizes[1] / DIM;
    const int E     = in_sizes[2];

    float* out = (float*)d_out;
    u16* q   = (u16*)d_ws;                              // n_dst x 128 bf16
    u8*  kv  = (u8*)(q + (size_t)n_dst * DIM);          // n_src x 384B (k fp8 | v bf16)
    u16* hag = (u16*)(kv + (size_t)n_src * KVREC);      // n_dst x 128 bf16
    int* seg = (int*)(hag + (size_t)n_dst * DIM);       // n_dst+1 ints
    size_t segEnd = ((size_t)(n_dst + 1) + 3) & ~(size_t)3;
    float* Wkv = (float*)(seg + segEnd);                // 256x128 fp32
    float* bkv = Wkv + 256 * DIM;                       // 256 fp32

    const int gq = (n_dst + BM - 1) / BM;
    const int gs = (n_src + BM - 1) / BM;

    seg_bounds<<<(E + 255) / 256, 256, 0, stream>>>(dst_idx, seg, E, n_dst);
    fold_relation_kv<<<256, DIM, 0, stream>>>(Wk, bk, Wv, bv, R, Wkv, bkv);
    proj_all<<<gq + gs, 256, 0, stream>>>(feat_src, feat_dst, Wq, bq, Wkv, bkv,
                                          q, kv, n_dst, n_src, gq);
    edge_attn9<<<(n_dst + 3) / 4, 256, 0, stream>>>(q, kv, src_idx, seg, hag, n_dst);
    gemm_mfma_b<<<gq, 256, 0, stream>>>(hag, Wo, bo, out, n_dst);
}

// Round 13
// 99.218 us; speedup vs baseline: 1.0572x; 1.0232x over previous
//
#include <hip/hip_runtime.h>
#include <math.h>

#define DIM 128
#define BM 64
#define LDB 136   // u16 row stride for bf16 W tile in LDS (272B)
#define KVREC 384 // bytes per kv record: 128B fp8 k + 256B bf16 v

typedef __attribute__((ext_vector_type(8))) short short8;
typedef __attribute__((ext_vector_type(4))) float f32x4;
typedef __attribute__((ext_vector_type(2))) float f32x2;
typedef unsigned short u16;
typedef unsigned int u32;
typedef unsigned char u8;

__device__ inline u16 f2bf(float f) {               // fp32 -> bf16 RNE
    union { float f; u32 u; } v; v.f = f;
    u32 r = v.u + 0x7fffu + ((v.u >> 16) & 1u);
    return (u16)(r >> 16);
}
__device__ inline float bfl(u32 u) { union { u32 u; float f; } v; v.u = u << 16; return v.f; }
__device__ inline float bfh(u32 u) { union { u32 u; float f; } v; v.u = u & 0xffff0000u; return v.f; }

// fp8 decode: dword w -> 4 floats fused into an fma chain (2 elems per cvt)
#define DEC_FMA(w, q0, q1, q2, q3, d) {                          \
    f32x2 lo_ = __builtin_amdgcn_cvt_pk_f32_fp8((w), false);     \
    f32x2 hi_ = __builtin_amdgcn_cvt_pk_f32_fp8((w), true);      \
    d = fmaf(lo_.x, q0, d); d = fmaf(lo_.y, q1, d);              \
    d = fmaf(hi_.x, q2, d); d = fmaf(hi_.y, q3, d); }

// pack 8 floats -> 8 fp8 bytes (uint2)
#define PACK8(x0,x1,x2,x3,x4,x5,x6,x7, out) {                    \
    int d0_ = __builtin_amdgcn_cvt_pk_fp8_f32(x0, x1, 0, false); \
    d0_ = __builtin_amdgcn_cvt_pk_fp8_f32(x2, x3, d0_, true);    \
    int d1_ = __builtin_amdgcn_cvt_pk_fp8_f32(x4, x5, 0, false); \
    d1_ = __builtin_amdgcn_cvt_pk_fp8_f32(x6, x7, d1_, true);    \
    out.x = (u32)d0_; out.y = (u32)d1_; }

// Wkv[0..127] = fold(R, Wk); Wkv[128..255] = Wv. bkv likewise.
// NOTE: Wv CANNOT be folded past the aggregation (per-head attention weights
// -- R11 post-mortem); v must materialize.
__global__ void fold_relation_kv(const float* __restrict__ Wk, const float* __restrict__ bk,
                                 const float* __restrict__ Wv, const float* __restrict__ bv,
                                 const float* __restrict__ R, float* __restrict__ Wkv,
                                 float* __restrict__ bkv) {
    const int o = blockIdx.x;   // 0..255
    const int t = threadIdx.x;  // 0..127
    if (o < 128) {
        const int h = o >> 4, e = o & 15;
        float acc = 0.f;
#pragma unroll
        for (int d = 0; d < 16; ++d)
            acc = fmaf(R[h * 256 + d * 16 + e], Wk[(size_t)(h * 16 + d) * DIM + t], acc);
        Wkv[(size_t)o * DIM + t] = acc;
        if (t == 0) {
            float bb = 0.f;
#pragma unroll
            for (int d = 0; d < 16; ++d) bb = fmaf(R[h * 256 + d * 16 + e], bk[h * 16 + d], bb);
            bkv[o] = bb;
        }
    } else {
        Wkv[(size_t)o * DIM + t] = Wv[(size_t)(o - 128) * DIM + t];
        if (t == 0) bkv[o] = bv[o - 128];
    }
}

// Fused projections + seg_bounds. Blocks [0,gq): q (bf16). [gq,gq+gs): k fp8
// + v bf16 record for one 64-row feat_src tile (X loaded once; two weight
// half-tiles staged sequentially). [gq+gs,...): seg_bounds. Weight rows
// permuted in LDS (row c -> slot (c%8)*16 + c/8) so each thread's 8 output
// cols are contiguous.
__global__ __launch_bounds__(256, 4)
void proj_all(const float* __restrict__ fsrc, const float* __restrict__ fdst,
              const float* __restrict__ Wq, const float* __restrict__ bq,
              const float* __restrict__ Wkv, const float* __restrict__ bkv,
              const int* __restrict__ didx, int* __restrict__ seg, int E,
              u16* __restrict__ qo, u8* __restrict__ kvo,
              int n_dst, int n_src, int gq, int gs) {
    __shared__ __align__(16) u16 wl[DIM * LDB];
    const int bid = blockIdx.x;
    const int tid = threadIdx.x;

    if (bid >= gq + gs) {      // ---- seg_bounds blocks ----
        int e = (bid - gq - gs) * 256 + tid;
        if (e < E) {
            int d = didx[e];
            int dp = (e == 0) ? -1 : didx[e - 1];
            for (int x = dp + 1; x <= d; ++x) seg[x] = e;
            if (e == E - 1)
                for (int x = d + 1; x <= n_dst; ++x) seg[x] = E;
        }
        return;
    }

    const bool isQ = bid < gq;
    const int tile = isQ ? bid : bid - gq;
    const float* X = isQ ? fdst : fsrc;
    const int n = isQ ? n_dst : n_src;

    const int lane = tid & 63, wave = tid >> 6;
    const int lrow = lane & 15, kg = lane >> 4;
    const int rbase = tile * BM + wave * 16;
    int xr = rbase + lrow; if (xr > n - 1) xr = n - 1;
    const float* xp = X + (size_t)xr * DIM + kg * 8;

    short8 af[4];
#pragma unroll
    for (int kc = 0; kc < 4; ++kc) {
        float4 a0 = *(const float4*)(xp + kc * 32);
        float4 a1 = *(const float4*)(xp + kc * 32 + 4);
        short8 u;
        u[0] = (short)f2bf(a0.x); u[1] = (short)f2bf(a0.y);
        u[2] = (short)f2bf(a0.z); u[3] = (short)f2bf(a0.w);
        u[4] = (short)f2bf(a1.x); u[5] = (short)f2bf(a1.y);
        u[6] = (short)f2bf(a1.z); u[7] = (short)f2bf(a1.w);
        af[kc] = u;
    }

    const float* W0 = isQ ? Wq : Wkv;
#pragma unroll
    for (int it = 0; it < 8; ++it) {
        int flat = it * 256 + tid;
        int c = flat >> 4, ck = flat & 15;
        int slot = (c & 7) * 16 + (c >> 3);
        const float4* s = (const float4*)&W0[(size_t)c * DIM + ck * 8];
        float4 f0 = s[0], f1 = s[1];
        short8 u;
        u[0] = (short)f2bf(f0.x); u[1] = (short)f2bf(f0.y);
        u[2] = (short)f2bf(f0.z); u[3] = (short)f2bf(f0.w);
        u[4] = (short)f2bf(f1.x); u[5] = (short)f2bf(f1.y);
        u[6] = (short)f2bf(f1.z); u[7] = (short)f2bf(f1.w);
        *(short8*)&wl[slot * LDB + ck * 8] = u;
    }
    __syncthreads();

    f32x4 acck[8];
#pragma unroll
    for (int j = 0; j < 8; ++j) acck[j] = (f32x4){0.f, 0.f, 0.f, 0.f};
#pragma unroll
    for (int kc = 0; kc < 4; ++kc)
#pragma unroll
        for (int j = 0; j < 8; ++j) {
            short8 bf = *(const short8*)&wl[(j * 16 + lrow) * LDB + kc * 32 + kg * 8];
            acck[j] = __builtin_amdgcn_mfma_f32_16x16x32_bf16(af[kc], bf, acck[j], 0, 0, 0);
        }

    f32x4 accv[8];
    if (!isQ) {
        __syncthreads();
#pragma unroll
        for (int it = 0; it < 8; ++it) {
            int flat = it * 256 + tid;
            int c = flat >> 4, ck = flat & 15;
            int slot = (c & 7) * 16 + (c >> 3);
            const float4* s = (const float4*)&Wkv[(size_t)(128 + c) * DIM + ck * 8];
            float4 f0 = s[0], f1 = s[1];
            short8 u;
            u[0] = (short)f2bf(f0.x); u[1] = (short)f2bf(f0.y);
            u[2] = (short)f2bf(f0.z); u[3] = (short)f2bf(f0.w);
            u[4] = (short)f2bf(f1.x); u[5] = (short)f2bf(f1.y);
            u[6] = (short)f2bf(f1.z); u[7] = (short)f2bf(f1.w);
            *(short8*)&wl[slot * LDB + ck * 8] = u;
        }
        __syncthreads();
#pragma unroll
        for (int j = 0; j < 8; ++j) accv[j] = (f32x4){0.f, 0.f, 0.f, 0.f};
#pragma unroll
        for (int kc = 0; kc < 4; ++kc)
#pragma unroll
            for (int j = 0; j < 8; ++j) {
                short8 bf = *(const short8*)&wl[(j * 16 + lrow) * LDB + kc * 32 + kg * 8];
                accv[j] = __builtin_amdgcn_mfma_f32_16x16x32_bf16(af[kc], bf, accv[j], 0, 0, 0);
            }
    }

    if (isQ) {
        float bias[8];
        *(float4*)&bias[0] = *(const float4*)&bq[lrow * 8];
        *(float4*)&bias[4] = *(const float4*)&bq[lrow * 8 + 4];
#pragma unroll
        for (int r = 0; r < 4; ++r) {
            int gr = rbase + kg * 4 + r;
            if (gr < n) {
                u16 o[8];
#pragma unroll
                for (int j = 0; j < 8; ++j) o[j] = f2bf(acck[j][r] + bias[j]);
                uint4 pk;
                pk.x = (u32)o[0] | ((u32)o[1] << 16);
                pk.y = (u32)o[2] | ((u32)o[3] << 16);
                pk.z = (u32)o[4] | ((u32)o[5] << 16);
                pk.w = (u32)o[6] | ((u32)o[7] << 16);
                *(uint4*)&qo[(size_t)gr * DIM + lrow * 8] = pk;
            }
        }
    } else {
        float bk_[8], bv_[8];
        *(float4*)&bk_[0] = *(const float4*)&bkv[lrow * 8];
        *(float4*)&bk_[4] = *(const float4*)&bkv[lrow * 8 + 4];
        *(float4*)&bv_[0] = *(const float4*)&bkv[128 + lrow * 8];
        *(float4*)&bv_[4] = *(const float4*)&bkv[128 + lrow * 8 + 4];
#pragma unroll
        for (int r = 0; r < 4; ++r) {
            int gr = rbase + kg * 4 + r;
            if (gr < n) {
                uint2 kd;
                PACK8(acck[0][r] + bk_[0], acck[1][r] + bk_[1], acck[2][r] + bk_[2],
                      acck[3][r] + bk_[3], acck[4][r] + bk_[4], acck[5][r] + bk_[5],
                      acck[6][r] + bk_[6], acck[7][r] + bk_[7], kd);
                u16 o[8];
#pragma unroll
                for (int j = 0; j < 8; ++j) o[j] = f2bf(accv[j][r] + bv_[j]);
                uint4 vd;
                vd.x = (u32)o[0] | ((u32)o[1] << 16);
                vd.y = (u32)o[2] | ((u32)o[3] << 16);
                vd.z = (u32)o[4] | ((u32)o[5] << 16);
                vd.w = (u32)o[6] | ((u32)o[7] << 16);
                u8* rec = kvo + (size_t)gr * KVREC;
                *(uint2*)(rec + lrow * 8) = kd;
                *(uint4*)(rec + 128 + lrow * 16) = vd;
            }
        }
    }
}

// ---- MFMA bf16 GEMM, bf16 X input, fp32 out (final projection) ----
__global__ __launch_bounds__(256, 4)
void gemm_mfma_b(const u16* __restrict__ X, const float* __restrict__ W,
                 const float* __restrict__ b, float* __restrict__ Y, int n) {
    __shared__ __align__(16) u16 wl[DIM * LDB];
    const int tid = threadIdx.x;
#pragma unroll
    for (int it = 0; it < 8; ++it) {
        int c8 = it * 256 + tid;
        int row = c8 >> 4, ck = c8 & 15;
        const float4* s = (const float4*)&W[(size_t)row * DIM + ck * 8];
        float4 f0 = s[0], f1 = s[1];
        short8 u;
        u[0] = (short)f2bf(f0.x); u[1] = (short)f2bf(f0.y);
        u[2] = (short)f2bf(f0.z); u[3] = (short)f2bf(f0.w);
        u[4] = (short)f2bf(f1.x); u[5] = (short)f2bf(f1.y);
        u[6] = (short)f2bf(f1.z); u[7] = (short)f2bf(f1.w);
        *(short8*)&wl[row * LDB + ck * 8] = u;
    }
    __syncthreads();
    const int lane = tid & 63, wave = tid >> 6;
    const int lrow = lane & 15, kg = lane >> 4;
    const int rbase = blockIdx.x * BM + wave * 16;
    int xr = rbase + lrow; if (xr > n - 1) xr = n - 1;
    const u16* xp = X + (size_t)xr * DIM + kg * 8;

    f32x4 acc[8];
#pragma unroll
    for (int j = 0; j < 8; ++j) acc[j] = (f32x4){0.f, 0.f, 0.f, 0.f};

#pragma unroll
    for (int kc = 0; kc < 4; ++kc) {
        short8 af = *(const short8*)(xp + kc * 32);
#pragma unroll
        for (int j = 0; j < 8; ++j) {
            short8 bf = *(const short8*)&wl[(j * 16 + lrow) * LDB + kc * 32 + kg * 8];
            acc[j] = __builtin_amdgcn_mfma_f32_16x16x32_bf16(af, bf, acc[j], 0, 0, 0);
        }
    }
#pragma unroll
    for (int r = 0; r < 4; ++r) {
        int gr = rbase + kg * 4 + r;
        if (gr < n) {
#pragma unroll
            for (int j = 0; j < 8; ++j) {
                int c = j * 16 + lrow;
                Y[(size_t)gr * DIM + c] = acc[j][r] + b[c];
            }
        }
    }
}

// ONE WAVE per dst, 4 dst per block. Thread = (edge slot g=lane>>3, head
// h=lane&7). 384B records: k fp8 (16B/head-lane), v bf16 (32B/head-lane).
// No LDS, no barriers in loop.
__global__ __launch_bounds__(256, 8)
void edge_attn9(const u16* __restrict__ q, const u8* __restrict__ kv,
                const int* __restrict__ sidx, const int* __restrict__ seg,
                u16* __restrict__ hout, int n_dst) {
    const int wave = threadIdx.x >> 6;
    const int lane = threadIdx.x & 63;
    const int dst = blockIdx.x * 4 + wave;
    if (dst >= n_dst) return;
    const int g = lane >> 3, h = lane & 7;

    const int s0 = seg[dst], s1 = seg[dst + 1];

    const uint4* qp = (const uint4*)q;
    uint4 qa = qp[(size_t)dst * 16 + h * 2];
    uint4 qb = qp[(size_t)dst * 16 + h * 2 + 1];
    float qf[16];
    qf[0]  = bfl(qa.x); qf[1]  = bfh(qa.x); qf[2]  = bfl(qa.y); qf[3]  = bfh(qa.y);
    qf[4]  = bfl(qa.z); qf[5]  = bfh(qa.z); qf[6]  = bfl(qa.w); qf[7]  = bfh(qa.w);
    qf[8]  = bfl(qb.x); qf[9]  = bfh(qb.x); qf[10] = bfl(qb.y); qf[11] = bfh(qb.y);
    qf[12] = bfl(qb.z); qf[13] = bfh(qb.z); qf[14] = bfl(qb.w); qf[15] = bfh(qb.w);

    float ssum = 0.f;
    float acc[16];
#pragma unroll
    for (int j = 0; j < 16; ++j) acc[j] = 0.f;

#pragma unroll 2
    for (int e = s0 + g; e < s1; e += 8) {
        const int row = sidx[e];
        const u8* rec = kv + (size_t)row * KVREC;
        uint4 k4 = *(const uint4*)(rec + h * 16);
        uint4 v0 = *(const uint4*)(rec + 128 + h * 32);
        uint4 v1 = *(const uint4*)(rec + 128 + h * 32 + 16);
        float d = 0.f;
        DEC_FMA(k4.x, qf[0],  qf[1],  qf[2],  qf[3],  d);
        DEC_FMA(k4.y, qf[4],  qf[5],  qf[6],  qf[7],  d);
        DEC_FMA(k4.z, qf[8],  qf[9],  qf[10], qf[11], d);
        DEC_FMA(k4.w, qf[12], qf[13], qf[14], qf[15], d);
        float lg = d * 0.25f;
        lg = (lg >= 0.f) ? lg : 0.2f * lg;
        const float p = __expf(lg);
        ssum += p;
        acc[0]  = fmaf(p, bfl(v0.x), acc[0]);  acc[1]  = fmaf(p, bfh(v0.x), acc[1]);
        acc[2]  = fmaf(p, bfl(v0.y), acc[2]);  acc[3]  = fmaf(p, bfh(v0.y), acc[3]);
        acc[4]  = fmaf(p, bfl(v0.z), acc[4]);  acc[5]  = fmaf(p, bfh(v0.z), acc[5]);
        acc[6]  = fmaf(p, bfl(v0.w), acc[6]);  acc[7]  = fmaf(p, bfh(v0.w), acc[7]);
        acc[8]  = fmaf(p, bfl(v1.x), acc[8]);  acc[9]  = fmaf(p, bfh(v1.x), acc[9]);
        acc[10] = fmaf(p, bfl(v1.y), acc[10]); acc[11] = fmaf(p, bfh(v1.y), acc[11]);
        acc[12] = fmaf(p, bfl(v1.z), acc[12]); acc[13] = fmaf(p, bfh(v1.z), acc[13]);
        acc[14] = fmaf(p, bfl(v1.w), acc[14]); acc[15] = fmaf(p, bfh(v1.w), acc[15]);
    }

#pragma unroll
    for (int j = 0; j < 16; ++j) {
        acc[j] += __shfl_xor(acc[j], 8);
        acc[j] += __shfl_xor(acc[j], 16);
        acc[j] += __shfl_xor(acc[j], 32);
    }
    ssum += __shfl_xor(ssum, 8);
    ssum += __shfl_xor(ssum, 16);
    ssum += __shfl_xor(ssum, 32);

    if (g == 0) {
        const float inv = (ssum > 0.f) ? 1.f / ssum : 0.f;
        u16 o[16];
#pragma unroll
        for (int j = 0; j < 16; ++j) o[j] = f2bf(acc[j] * inv);
        uint4 pa, pb;
        pa.x = (u32)o[0]  | ((u32)o[1]  << 16);
        pa.y = (u32)o[2]  | ((u32)o[3]  << 16);
        pa.z = (u32)o[4]  | ((u32)o[5]  << 16);
        pa.w = (u32)o[6]  | ((u32)o[7]  << 16);
        pb.x = (u32)o[8]  | ((u32)o[9]  << 16);
        pb.y = (u32)o[10] | ((u32)o[11] << 16);
        pb.z = (u32)o[12] | ((u32)o[13] << 16);
        pb.w = (u32)o[14] | ((u32)o[15] << 16);
        ((uint4*)hout)[(size_t)dst * 16 + h * 2]     = pa;
        ((uint4*)hout)[(size_t)dst * 16 + h * 2 + 1] = pb;
    }
}

extern "C" void kernel_launch(void* const* d_in, const int* in_sizes, int n_in,
                              void* d_out, int out_size, void* d_ws, size_t ws_size,
                              hipStream_t stream) {
    const float* feat_src = (const float*)d_in[0];
    const float* feat_dst = (const float*)d_in[1];
    const int*   src_idx  = (const int*)d_in[2];
    const int*   dst_idx  = (const int*)d_in[3];
    const float* Wq = (const float*)d_in[4];
    const float* bq = (const float*)d_in[5];
    const float* Wk = (const float*)d_in[6];
    const float* bk = (const float*)d_in[7];
    const float* Wv = (const float*)d_in[8];
    const float* bv = (const float*)d_in[9];
    const float* R  = (const float*)d_in[10];
    const float* Wo = (const float*)d_in[11];
    const float* bo = (const float*)d_in[12];

    const int n_src = in_sizes[0] / DIM;
    const int n_dst = in_sizes[1] / DIM;
    const int E     = in_sizes[2];

    float* out = (float*)d_out;
    u16* q   = (u16*)d_ws;                              // n_dst x 128 bf16
    u8*  kv  = (u8*)(q + (size_t)n_dst * DIM);          // n_src x 384B (k fp8 | v bf16)
    u16* hag = (u16*)(kv + (size_t)n_src * KVREC);      // n_dst x 128 bf16
    int* seg = (int*)(hag + (size_t)n_dst * DIM);       // n_dst+1 ints
    size_t segEnd = ((size_t)(n_dst + 1) + 3) & ~(size_t)3;
    float* Wkv = (float*)(seg + segEnd);                // 256x128 fp32
    float* bkv = Wkv + 256 * DIM;                       // 256 fp32

    const int gq = (n_dst + BM - 1) / BM;
    const int gs = (n_src + BM - 1) / BM;
    const int gE = (E + 255) / 256;

    fold_relation_kv<<<256, DIM, 0, stream>>>(Wk, bk, Wv, bv, R, Wkv, bkv);
    proj_all<<<gq + gs + gE, 256, 0, stream>>>(feat_src, feat_dst, Wq, bq, Wkv, bkv,
                                               dst_idx, seg, E, q, kv, n_dst, n_src, gq, gs);
    edge_attn9<<<(n_dst + 3) / 4, 256, 0, stream>>>(q, kv, src_idx, seg, hag, n_dst);
    gemm_mfma_b<<<gq, 256, 0, stream>>>(hag, Wo, bo, out, n_dst);
}

// Round 14
// 86.303 us; speedup vs baseline: 1.2153x; 1.1496x over previous
//
#include <hip/hip_runtime.h>
#include <math.h>

#define DIM 128
#define BM 64
#define LDB 136   // u16 row stride for bf16 W tile in LDS (272B)
#define KVREC 384 // bytes per kv record: 128B fp8 k + 256B bf16 v

typedef __attribute__((ext_vector_type(8))) short short8;
typedef __attribute__((ext_vector_type(4))) float f32x4;
typedef __attribute__((ext_vector_type(2))) float f32x2;
typedef unsigned short u16;
typedef unsigned int u32;
typedef unsigned char u8;

__device__ inline u16 f2bf(float f) {               // fp32 -> bf16 RNE
    union { float f; u32 u; } v; v.f = f;
    u32 r = v.u + 0x7fffu + ((v.u >> 16) & 1u);
    return (u16)(r >> 16);
}
__device__ inline float bfl(u32 u) { union { u32 u; float f; } v; v.u = u << 16; return v.f; }
__device__ inline float bfh(u32 u) { union { u32 u; float f; } v; v.u = u & 0xffff0000u; return v.f; }

// fp8 decode: dword w -> 4 floats fused into an fma chain (2 elems per cvt)
#define DEC_FMA(w, q0, q1, q2, q3, d) {                          \
    f32x2 lo_ = __builtin_amdgcn_cvt_pk_f32_fp8((w), false);     \
    f32x2 hi_ = __builtin_amdgcn_cvt_pk_f32_fp8((w), true);      \
    d = fmaf(lo_.x, q0, d); d = fmaf(lo_.y, q1, d);              \
    d = fmaf(hi_.x, q2, d); d = fmaf(hi_.y, q3, d); }

// fp8 decode: dword w -> 4 floats
#define DEC4(w, o0, o1, o2, o3) {                                \
    f32x2 lo_ = __builtin_amdgcn_cvt_pk_f32_fp8((w), false);     \
    f32x2 hi_ = __builtin_amdgcn_cvt_pk_f32_fp8((w), true);      \
    o0 = lo_.x; o1 = lo_.y; o2 = hi_.x; o3 = hi_.y; }

// pack 8 floats -> 8 fp8 bytes (uint2)
#define PACK8(x0,x1,x2,x3,x4,x5,x6,x7, out) {                    \
    int d0_ = __builtin_amdgcn_cvt_pk_fp8_f32(x0, x1, 0, false); \
    d0_ = __builtin_amdgcn_cvt_pk_fp8_f32(x2, x3, d0_, true);    \
    int d1_ = __builtin_amdgcn_cvt_pk_fp8_f32(x4, x5, 0, false); \
    d1_ = __builtin_amdgcn_cvt_pk_fp8_f32(x6, x7, d1_, true);    \
    out.x = (u32)d0_; out.y = (u32)d1_; }

// Wkv[0..127] = fold(R, Wk); Wkv[128..255] = Wv. bkv likewise.
// NOTE: Wv CANNOT be folded past the aggregation (per-head attention weights
// -- R11 post-mortem); v must materialize, and in bf16 (fp8 v fails: its
// ~4% relative error enters the output linearly -- R9 post-mortem).
__global__ void fold_relation_kv(const float* __restrict__ Wk, const float* __restrict__ bk,
                                 const float* __restrict__ Wv, const float* __restrict__ bv,
                                 const float* __restrict__ R, float* __restrict__ Wkv,
                                 float* __restrict__ bkv) {
    const int o = blockIdx.x;   // 0..255
    const int t = threadIdx.x;  // 0..127
    if (o < 128) {
        const int h = o >> 4, e = o & 15;
        float acc = 0.f;
#pragma unroll
        for (int d = 0; d < 16; ++d)
            acc = fmaf(R[h * 256 + d * 16 + e], Wk[(size_t)(h * 16 + d) * DIM + t], acc);
        Wkv[(size_t)o * DIM + t] = acc;
        if (t == 0) {
            float bb = 0.f;
#pragma unroll
            for (int d = 0; d < 16; ++d) bb = fmaf(R[h * 256 + d * 16 + e], bk[h * 16 + d], bb);
            bkv[o] = bb;
        }
    } else {
        Wkv[(size_t)o * DIM + t] = Wv[(size_t)(o - 128) * DIM + t];
        if (t == 0) bkv[o] = bv[o - 128];
    }
}

// Fused projections + seg_bounds. Blocks [0,gq): q (fp8 out). [gq,gq+gs):
// k fp8 + v bf16 record for one 64-row feat_src tile (X loaded once; two
// weight half-tiles staged sequentially). [gq+gs,...): seg_bounds. Weight
// rows permuted in LDS (row c -> slot (c%8)*16 + c/8) so each thread's 8
// output cols are contiguous.
__global__ __launch_bounds__(256, 4)
void proj_all(const float* __restrict__ fsrc, const float* __restrict__ fdst,
              const float* __restrict__ Wq, const float* __restrict__ bq,
              const float* __restrict__ Wkv, const float* __restrict__ bkv,
              const int* __restrict__ didx, int* __restrict__ seg, int E,
              u8* __restrict__ qo, u8* __restrict__ kvo,
              int n_dst, int n_src, int gq, int gs) {
    __shared__ __align__(16) u16 wl[DIM * LDB];
    const int bid = blockIdx.x;
    const int tid = threadIdx.x;

    if (bid >= gq + gs) {      // ---- seg_bounds blocks ----
        int e = (bid - gq - gs) * 256 + tid;
        if (e < E) {
            int d = didx[e];
            int dp = (e == 0) ? -1 : didx[e - 1];
            for (int x = dp + 1; x <= d; ++x) seg[x] = e;
            if (e == E - 1)
                for (int x = d + 1; x <= n_dst; ++x) seg[x] = E;
        }
        return;
    }

    const bool isQ = bid < gq;
    const int tile = isQ ? bid : bid - gq;
    const float* X = isQ ? fdst : fsrc;
    const int n = isQ ? n_dst : n_src;

    const int lane = tid & 63, wave = tid >> 6;
    const int lrow = lane & 15, kg = lane >> 4;
    const int rbase = tile * BM + wave * 16;
    int xr = rbase + lrow; if (xr > n - 1) xr = n - 1;
    const float* xp = X + (size_t)xr * DIM + kg * 8;

    short8 af[4];
#pragma unroll
    for (int kc = 0; kc < 4; ++kc) {
        float4 a0 = *(const float4*)(xp + kc * 32);
        float4 a1 = *(const float4*)(xp + kc * 32 + 4);
        short8 u;
        u[0] = (short)f2bf(a0.x); u[1] = (short)f2bf(a0.y);
        u[2] = (short)f2bf(a0.z); u[3] = (short)f2bf(a0.w);
        u[4] = (short)f2bf(a1.x); u[5] = (short)f2bf(a1.y);
        u[6] = (short)f2bf(a1.z); u[7] = (short)f2bf(a1.w);
        af[kc] = u;
    }

    const float* W0 = isQ ? Wq : Wkv;
#pragma unroll
    for (int it = 0; it < 8; ++it) {
        int flat = it * 256 + tid;
        int c = flat >> 4, ck = flat & 15;
        int slot = (c & 7) * 16 + (c >> 3);
        const float4* s = (const float4*)&W0[(size_t)c * DIM + ck * 8];
        float4 f0 = s[0], f1 = s[1];
        short8 u;
        u[0] = (short)f2bf(f0.x); u[1] = (short)f2bf(f0.y);
        u[2] = (short)f2bf(f0.z); u[3] = (short)f2bf(f0.w);
        u[4] = (short)f2bf(f1.x); u[5] = (short)f2bf(f1.y);
        u[6] = (short)f2bf(f1.z); u[7] = (short)f2bf(f1.w);
        *(short8*)&wl[slot * LDB + ck * 8] = u;
    }
    __syncthreads();

    f32x4 acck[8];
#pragma unroll
    for (int j = 0; j < 8; ++j) acck[j] = (f32x4){0.f, 0.f, 0.f, 0.f};
#pragma unroll
    for (int kc = 0; kc < 4; ++kc)
#pragma unroll
        for (int j = 0; j < 8; ++j) {
            short8 bf = *(const short8*)&wl[(j * 16 + lrow) * LDB + kc * 32 + kg * 8];
            acck[j] = __builtin_amdgcn_mfma_f32_16x16x32_bf16(af[kc], bf, acck[j], 0, 0, 0);
        }

    f32x4 accv[8];
    if (!isQ) {
        __syncthreads();
#pragma unroll
        for (int it = 0; it < 8; ++it) {
            int flat = it * 256 + tid;
            int c = flat >> 4, ck = flat & 15;
            int slot = (c & 7) * 16 + (c >> 3);
            const float4* s = (const float4*)&Wkv[(size_t)(128 + c) * DIM + ck * 8];
            float4 f0 = s[0], f1 = s[1];
            short8 u;
            u[0] = (short)f2bf(f0.x); u[1] = (short)f2bf(f0.y);
            u[2] = (short)f2bf(f0.z); u[3] = (short)f2bf(f0.w);
            u[4] = (short)f2bf(f1.x); u[5] = (short)f2bf(f1.y);
            u[6] = (short)f2bf(f1.z); u[7] = (short)f2bf(f1.w);
            *(short8*)&wl[slot * LDB + ck * 8] = u;
        }
        __syncthreads();
#pragma unroll
        for (int j = 0; j < 8; ++j) accv[j] = (f32x4){0.f, 0.f, 0.f, 0.f};
#pragma unroll
        for (int kc = 0; kc < 4; ++kc)
#pragma unroll
            for (int j = 0; j < 8; ++j) {
                short8 bf = *(const short8*)&wl[(j * 16 + lrow) * LDB + kc * 32 + kg * 8];
                accv[j] = __builtin_amdgcn_mfma_f32_16x16x32_bf16(af[kc], bf, accv[j], 0, 0, 0);
            }
    }

    if (isQ) {
        float bias[8];
        *(float4*)&bias[0] = *(const float4*)&bq[lrow * 8];
        *(float4*)&bias[4] = *(const float4*)&bq[lrow * 8 + 4];
#pragma unroll
        for (int r = 0; r < 4; ++r) {
            int gr = rbase + kg * 4 + r;
            if (gr < n) {
                uint2 qd;
                PACK8(acck[0][r] + bias[0], acck[1][r] + bias[1], acck[2][r] + bias[2],
                      acck[3][r] + bias[3], acck[4][r] + bias[4], acck[5][r] + bias[5],
                      acck[6][r] + bias[6], acck[7][r] + bias[7], qd);
                *(uint2*)&qo[(size_t)gr * 128 + lrow * 8] = qd;
            }
        }
    } else {
        float bk_[8], bv_[8];
        *(float4*)&bk_[0] = *(const float4*)&bkv[lrow * 8];
        *(float4*)&bk_[4] = *(const float4*)&bkv[lrow * 8 + 4];
        *(float4*)&bv_[0] = *(const float4*)&bkv[128 + lrow * 8];
        *(float4*)&bv_[4] = *(const float4*)&bkv[128 + lrow * 8 + 4];
#pragma unroll
        for (int r = 0; r < 4; ++r) {
            int gr = rbase + kg * 4 + r;
            if (gr < n) {
                uint2 kd;
                PACK8(acck[0][r] + bk_[0], acck[1][r] + bk_[1], acck[2][r] + bk_[2],
                      acck[3][r] + bk_[3], acck[4][r] + bk_[4], acck[5][r] + bk_[5],
                      acck[6][r] + bk_[6], acck[7][r] + bk_[7], kd);
                u16 o[8];
#pragma unroll
                for (int j = 0; j < 8; ++j) o[j] = f2bf(accv[j][r] + bv_[j]);
                uint4 vd;
                vd.x = (u32)o[0] | ((u32)o[1] << 16);
                vd.y = (u32)o[2] | ((u32)o[3] << 16);
                vd.z = (u32)o[4] | ((u32)o[5] << 16);
                vd.w = (u32)o[6] | ((u32)o[7] << 16);
                u8* rec = kvo + (size_t)gr * KVREC;
                *(uint2*)(rec + lrow * 8) = kd;
                *(uint4*)(rec + 128 + lrow * 16) = vd;
            }
        }
    }
}

// ---- MFMA bf16 GEMM, bf16 X input, fp32 out (final projection) ----
__global__ __launch_bounds__(256, 4)
void gemm_mfma_b(const u16* __restrict__ X, const float* __restrict__ W,
                 const float* __restrict__ b, float* __restrict__ Y, int n) {
    __shared__ __align__(16) u16 wl[DIM * LDB];
    const int tid = threadIdx.x;
#pragma unroll
    for (int it = 0; it < 8; ++it) {
        int c8 = it * 256 + tid;
        int row = c8 >> 4, ck = c8 & 15;
        const float4* s = (const float4*)&W[(size_t)row * DIM + ck * 8];
        float4 f0 = s[0], f1 = s[1];
        short8 u;
        u[0] = (short)f2bf(f0.x); u[1] = (short)f2bf(f0.y);
        u[2] = (short)f2bf(f0.z); u[3] = (short)f2bf(f0.w);
        u[4] = (short)f2bf(f1.x); u[5] = (short)f2bf(f1.y);
        u[6] = (short)f2bf(f1.z); u[7] = (short)f2bf(f1.w);
        *(short8*)&wl[row * LDB + ck * 8] = u;
    }
    __syncthreads();
    const int lane = tid & 63, wave = tid >> 6;
    const int lrow = lane & 15, kg = lane >> 4;
    const int rbase = blockIdx.x * BM + wave * 16;
    int xr = rbase + lrow; if (xr > n - 1) xr = n - 1;
    const u16* xp = X + (size_t)xr * DIM + kg * 8;

    f32x4 acc[8];
#pragma unroll
    for (int j = 0; j < 8; ++j) acc[j] = (f32x4){0.f, 0.f, 0.f, 0.f};

#pragma unroll
    for (int kc = 0; kc < 4; ++kc) {
        short8 af = *(const short8*)(xp + kc * 32);
#pragma unroll
        for (int j = 0; j < 8; ++j) {
            short8 bf = *(const short8*)&wl[(j * 16 + lrow) * LDB + kc * 32 + kg * 8];
            acc[j] = __builtin_amdgcn_mfma_f32_16x16x32_bf16(af, bf, acc[j], 0, 0, 0);
        }
    }
#pragma unroll
    for (int r = 0; r < 4; ++r) {
        int gr = rbase + kg * 4 + r;
        if (gr < n) {
#pragma unroll
            for (int j = 0; j < 8; ++j) {
                int c = j * 16 + lrow;
                Y[(size_t)gr * DIM + c] = acc[j][r] + b[c];
            }
        }
    }
}

// ONE WAVE per dst, 4 dst per block. Thread = (edge slot g=lane>>3, head
// h=lane&7). q fp8 (16B/head), 384B kv records: k fp8 (16B/head-lane),
// v bf16 (32B/head-lane). No LDS, no barriers in loop.
__global__ __launch_bounds__(256, 8)
void edge_attn10(const u8* __restrict__ q, const u8* __restrict__ kv,
                 const int* __restrict__ sidx, const int* __restrict__ seg,
                 u16* __restrict__ hout, int n_dst) {
    const int wave = threadIdx.x >> 6;
    const int lane = threadIdx.x & 63;
    const int dst = blockIdx.x * 4 + wave;
    if (dst >= n_dst) return;
    const int g = lane >> 3, h = lane & 7;

    const int s0 = seg[dst], s1 = seg[dst + 1];

    // this head's 16 q values (16B fp8 -> 16 fp32 via 8 cvt_pk)
    uint4 qa = *(const uint4*)(q + (size_t)dst * 128 + h * 16);
    float qf[16];
    DEC4(qa.x, qf[0],  qf[1],  qf[2],  qf[3]);
    DEC4(qa.y, qf[4],  qf[5],  qf[6],  qf[7]);
    DEC4(qa.z, qf[8],  qf[9],  qf[10], qf[11]);
    DEC4(qa.w, qf[12], qf[13], qf[14], qf[15]);

    float ssum = 0.f;
    float acc[16];
#pragma unroll
    for (int j = 0; j < 16; ++j) acc[j] = 0.f;

#pragma unroll 2
    for (int e = s0 + g; e < s1; e += 8) {
        const int row = sidx[e];
        const u8* rec = kv + (size_t)row * KVREC;
        uint4 k4 = *(const uint4*)(rec + h * 16);
        uint4 v0 = *(const uint4*)(rec + 128 + h * 32);
        uint4 v1 = *(const uint4*)(rec + 128 + h * 32 + 16);
        float d = 0.f;
        DEC_FMA(k4.x, qf[0],  qf[1],  qf[2],  qf[3],  d);
        DEC_FMA(k4.y, qf[4],  qf[5],  qf[6],  qf[7],  d);
        DEC_FMA(k4.z, qf[8],  qf[9],  qf[10], qf[11], d);
        DEC_FMA(k4.w, qf[12], qf[13], qf[14], qf[15], d);
        float lg = d * 0.25f;
        lg = (lg >= 0.f) ? lg : 0.2f * lg;
        const float p = __expf(lg);
        ssum += p;
        acc[0]  = fmaf(p, bfl(v0.x), acc[0]);  acc[1]  = fmaf(p, bfh(v0.x), acc[1]);
        acc[2]  = fmaf(p, bfl(v0.y), acc[2]);  acc[3]  = fmaf(p, bfh(v0.y), acc[3]);
        acc[4]  = fmaf(p, bfl(v0.z), acc[4]);  acc[5]  = fmaf(p, bfh(v0.z), acc[5]);
        acc[6]  = fmaf(p, bfl(v0.w), acc[6]);  acc[7]  = fmaf(p, bfh(v0.w), acc[7]);
        acc[8]  = fmaf(p, bfl(v1.x), acc[8]);  acc[9]  = fmaf(p, bfh(v1.x), acc[9]);
        acc[10] = fmaf(p, bfl(v1.y), acc[10]); acc[11] = fmaf(p, bfh(v1.y), acc[11]);
        acc[12] = fmaf(p, bfl(v1.z), acc[12]); acc[13] = fmaf(p, bfh(v1.z), acc[13]);
        acc[14] = fmaf(p, bfl(v1.w), acc[14]); acc[15] = fmaf(p, bfh(v1.w), acc[15]);
    }

#pragma unroll
    for (int j = 0; j < 16; ++j) {
        acc[j] += __shfl_xor(acc[j], 8);
        acc[j] += __shfl_xor(acc[j], 16);
        acc[j] += __shfl_xor(acc[j], 32);
    }
    ssum += __shfl_xor(ssum, 8);
    ssum += __shfl_xor(ssum, 16);
    ssum += __shfl_xor(ssum, 32);

    if (g == 0) {
        const float inv = (ssum > 0.f) ? 1.f / ssum : 0.f;
        u16 o[16];
#pragma unroll
        for (int j = 0; j < 16; ++j) o[j] = f2bf(acc[j] * inv);
        uint4 pa, pb;
        pa.x = (u32)o[0]  | ((u32)o[1]  << 16);
        pa.y = (u32)o[2]  | ((u32)o[3]  << 16);
        pa.z = (u32)o[4]  | ((u32)o[5]  << 16);
        pa.w = (u32)o[6]  | ((u32)o[7]  << 16);
        pb.x = (u32)o[8]  | ((u32)o[9]  << 16);
        pb.y = (u32)o[10] | ((u32)o[11] << 16);
        pb.z = (u32)o[12] | ((u32)o[13] << 16);
        pb.w = (u32)o[14] | ((u32)o[15] << 16);
        ((uint4*)hout)[(size_t)dst * 16 + h * 2]     = pa;
        ((uint4*)hout)[(size_t)dst * 16 + h * 2 + 1] = pb;
    }
}

extern "C" void kernel_launch(void* const* d_in, const int* in_sizes, int n_in,
                              void* d_out, int out_size, void* d_ws, size_t ws_size,
                              hipStream_t stream) {
    const float* feat_src = (const float*)d_in[0];
    const float* feat_dst = (const float*)d_in[1];
    const int*   src_idx  = (const int*)d_in[2];
    const int*   dst_idx  = (const int*)d_in[3];
    const float* Wq = (const float*)d_in[4];
    const float* bq = (const float*)d_in[5];
    const float* Wk = (const float*)d_in[6];
    const float* bk = (const float*)d_in[7];
    const float* Wv = (const float*)d_in[8];
    const float* bv = (const float*)d_in[9];
    const float* R  = (const float*)d_in[10];
    const float* Wo = (const float*)d_in[11];
    const float* bo = (const float*)d_in[12];

    const int n_src = in_sizes[0] / DIM;
    const int n_dst = in_sizes[1] / DIM;
    const int E     = in_sizes[2];

    float* out = (float*)d_out;
    u8*  q   = (u8*)d_ws;                               // n_dst x 128 fp8
    u8*  kv  = q + (size_t)n_dst * 128;                 // n_src x 384B (k fp8 | v bf16)
    u16* hag = (u16*)(kv + (size_t)n_src * KVREC);      // n_dst x 128 bf16
    int* seg = (int*)(hag + (size_t)n_dst * DIM);       // n_dst+1 ints
    size_t segEnd = ((size_t)(n_dst + 1) + 3) & ~(size_t)3;
    float* Wkv = (float*)(seg + segEnd);                // 256x128 fp32
    float* bkv = Wkv + 256 * DIM;                       // 256 fp32

    const int gq = (n_dst + BM - 1) / BM;
    const int gs = (n_src + BM - 1) / BM;
    const int gE = (E + 255) / 256;

    fold_relation_kv<<<256, DIM, 0, stream>>>(Wk, bk, Wv, bv, R, Wkv, bkv);
    proj_all<<<gq + gs + gE, 256, 0, stream>>>(feat_src, feat_dst, Wq, bq, Wkv, bkv,
                                               dst_idx, seg, E, q, kv, n_dst, n_src, gq, gs);
    edge_attn10<<<(n_dst + 3) / 4, 256, 0, stream>>>(q, kv, src_idx, seg, hag, n_dst);
    gemm_mfma_b<<<gq, 256, 0, stream>>>(hag, Wo, bo, out, n_dst);
}